// Round 1
// baseline (1384.538 us; speedup 1.0000x reference)
//
#include <hip/hip_runtime.h>
#include <stdint.h>

// LSTM cell: B=16384, IN=1024, H=1024, fp32 in/out.
// Strategy: split-bf16 (hi/lo) MFMA GEMM, gate-interleaved weight packing
// (n = 4*h + g), fused activation epilogue via 4-lane shfl_xor exchange.

#define BB 16384
#define KK 2048
#define HH 1024
#define NN 4096  // 4 gates interleaved

typedef float  f32x4  __attribute__((ext_vector_type(4)));
typedef __bf16 bf16x8 __attribute__((ext_vector_type(8)));
typedef short  s16x8  __attribute__((ext_vector_type(8)));

__device__ __forceinline__ ushort f2bf(float f) {
  uint32_t x = __float_as_uint(f);
  x += 0x7fffu + ((x >> 16) & 1u);
  return (ushort)(x >> 16);
}
__device__ __forceinline__ float bf2f(ushort h) {
  return __uint_as_float(((uint32_t)h) << 16);
}

// split 8 contiguous floats into bf16 hi + bf16 residual lo
__device__ __forceinline__ void split8(const float* __restrict__ src, s16x8* hi, s16x8* lo) {
  float4 v0 = *(const float4*)src;
  float4 v1 = *(const float4*)(src + 4);
  float f[8] = {v0.x, v0.y, v0.z, v0.w, v1.x, v1.y, v1.z, v1.w};
  s16x8 h, l;
#pragma unroll
  for (int j = 0; j < 8; ++j) {
    ushort hb = f2bf(f[j]);
    float  r  = f[j] - bf2f(hb);
    h[j] = (short)hb;
    l[j] = (short)f2bf(r);
  }
  *hi = h; *lo = l;
}

// ---- prep: A = [x | h_prev] (B x 2048) -> A_hi/A_lo, k-group swizzled ----
// global layout: A[b][k ^ (((b>>1)&3)<<3)] so GEMM staging is linear and
// LDS reads are ~conflict-free (rule #21: swizzle both sides via source).
__global__ void prep_A(const float* __restrict__ x, const float* __restrict__ hp,
                       ushort* __restrict__ Ahi, ushort* __restrict__ Alo) {
  size_t i8 = ((size_t)blockIdx.x * 256 + threadIdx.x) * 8;  // < BB*KK
  int b = (int)(i8 >> 11);
  int k = (int)(i8 & 2047);
  const float* src = (k < 1024) ? (x + (size_t)b * 1024 + k)
                                : (hp + (size_t)b * 1024 + (k - 1024));
  s16x8 h, l;
  split8(src, &h, &l);
  int swz = (b >> 1) & 3;
  size_t dst = (size_t)b * KK + (size_t)(k ^ (swz << 3));
  *(s16x8*)(Ahi + dst) = h;
  *(s16x8*)(Alo + dst) = l;
}

// ---- prep: W packed gate-interleaved: Wp[n][k], n = 4*h + g ----
__global__ void prep_W(const float* __restrict__ Wf, const float* __restrict__ Wi,
                       const float* __restrict__ Wg, const float* __restrict__ Wo,
                       const float* __restrict__ bf_, const float* __restrict__ bi_,
                       const float* __restrict__ bg_, const float* __restrict__ bo_,
                       ushort* __restrict__ Whi, ushort* __restrict__ Wlo,
                       float* __restrict__ bpack) {
  size_t i8 = ((size_t)blockIdx.x * 256 + threadIdx.x) * 8;  // < NN*KK
  int n = (int)(i8 >> 11);
  int k = (int)(i8 & 2047);
  int g = n & 3, h = n >> 2;
  const float* w = (g == 0) ? Wf : (g == 1) ? Wi : (g == 2) ? Wg : Wo;
  s16x8 hi, lo;
  split8(w + (size_t)h * KK + k, &hi, &lo);
  int swz = (n >> 1) & 3;
  size_t dst = (size_t)n * KK + (size_t)(k ^ (swz << 3));
  *(s16x8*)(Whi + dst) = hi;
  *(s16x8*)(Wlo + dst) = lo;
  if (k == 0) {
    const float* bb = (g == 0) ? bf_ : (g == 1) ? bi_ : (g == 2) ? bg_ : bo_;
    bpack[n] = bb[h];
  }
}

// CK-style addrspace cast for global_load_lds
__device__ __forceinline__ void gl2lds16(const ushort* g, ushort* l) {
  auto gp = reinterpret_cast<const __attribute__((address_space(1))) uint32_t*>(
      reinterpret_cast<uintptr_t>(g));
  auto lp = reinterpret_cast<__attribute__((address_space(3))) uint32_t*>(
      reinterpret_cast<uintptr_t>(l));
  __builtin_amdgcn_global_load_lds(gp, lp, 16, 0, 0);
}

// ---- fused GEMM + LSTM epilogue ----
// tile 128(M) x 128(N), BK=32, 4 waves (2x2), each wave 64x64 via 4x4 frags
// of mfma_f32_16x16x32_bf16; 3 MFMA per frag (hh, hl, lh) for fp32 accuracy.
__global__ __launch_bounds__(256) void lstm_gemm(
    const ushort* __restrict__ Ahi, const ushort* __restrict__ Alo,
    const ushort* __restrict__ Whi, const ushort* __restrict__ Wlo,
    const float* __restrict__ bpack, const float* __restrict__ c_prev,
    float* __restrict__ out) {
  __shared__ ushort lds[4][128 * 32];  // Ahi, Alo, Bhi, Blo : 32 KiB

  int t = threadIdx.x;
  int lane = t & 63;
  int wave = t >> 6;
  int wm = wave >> 1, wn = wave & 1;
  int mbase = blockIdx.y * 128;
  int nbase = blockIdx.x * 128;

  f32x4 acc[4][4];
#pragma unroll
  for (int mi = 0; mi < 4; ++mi)
#pragma unroll
    for (int ni = 0; ni < 4; ++ni) acc[mi][ni] = f32x4{0.f, 0.f, 0.f, 0.f};

  int lr = lane & 15;                       // frag row (A: m, B: n)
  int uo = ((lane >> 4) ^ ((lane >> 1) & 3)) * 8;  // swizzled k-group offset
  int srow = t >> 2;                        // staging row within 64-row chunk
  int su = t & 3;                           // staging 16B slot within row
  int ldsw = (t & ~63) * 8;                 // wave-uniform LDS elem base

  for (int kt = 0; kt < KK / 32; ++kt) {
    int ko = kt * 32;
#pragma unroll
    for (int c = 0; c < 2; ++c) {
      int row = c * 64 + srow;
      size_t aoff = (size_t)(mbase + row) * KK + ko + su * 8;
      size_t boff = (size_t)(nbase + row) * KK + ko + su * 8;
      int lo_ = c * 2048 + ldsw;
      gl2lds16(Ahi + aoff, &lds[0][lo_]);
      gl2lds16(Alo + aoff, &lds[1][lo_]);
      gl2lds16(Whi + boff, &lds[2][lo_]);
      gl2lds16(Wlo + boff, &lds[3][lo_]);
    }
    __syncthreads();  // compiler emits vmcnt(0) before s_barrier

    s16x8 ah[4], al[4], bh[4], bl[4];
#pragma unroll
    for (int mi = 0; mi < 4; ++mi) {
      int off = (wm * 64 + mi * 16 + lr) * 32 + uo;
      ah[mi] = *(const s16x8*)&lds[0][off];
      al[mi] = *(const s16x8*)&lds[1][off];
    }
#pragma unroll
    for (int ni = 0; ni < 4; ++ni) {
      int off = (wn * 64 + ni * 16 + lr) * 32 + uo;
      bh[ni] = *(const s16x8*)&lds[2][off];
      bl[ni] = *(const s16x8*)&lds[3][off];
    }
#pragma unroll
    for (int mi = 0; mi < 4; ++mi)
#pragma unroll
      for (int ni = 0; ni < 4; ++ni) {
        bf16x8 a_h = __builtin_bit_cast(bf16x8, ah[mi]);
        bf16x8 a_l = __builtin_bit_cast(bf16x8, al[mi]);
        bf16x8 b_h = __builtin_bit_cast(bf16x8, bh[ni]);
        bf16x8 b_l = __builtin_bit_cast(bf16x8, bl[ni]);
        acc[mi][ni] = __builtin_amdgcn_mfma_f32_16x16x32_bf16(a_h, b_h, acc[mi][ni], 0, 0, 0);
        acc[mi][ni] = __builtin_amdgcn_mfma_f32_16x16x32_bf16(a_h, b_l, acc[mi][ni], 0, 0, 0);
        acc[mi][ni] = __builtin_amdgcn_mfma_f32_16x16x32_bf16(a_l, b_h, acc[mi][ni], 0, 0, 0);
      }
    __syncthreads();  // protect LDS reuse
  }

  // epilogue: C/D layout col=lane&15 (n), row=(lane>>4)*4+reg (m)  [m89]
  int g = lr & 3;
#pragma unroll
  for (int mi = 0; mi < 4; ++mi)
#pragma unroll
    for (int ni = 0; ni < 4; ++ni) {
      int n_g = nbase + wn * 64 + ni * 16 + lr;
      float bias = bpack[n_g];
      int h = n_g >> 2;
      int m0 = mbase + wm * 64 + mi * 16 + (lane >> 4) * 4;
#pragma unroll
      for (int r = 0; r < 4; ++r) {
        float v = acc[mi][ni][r] + bias;
        float t1 = __shfl_xor(v, 1, 64);  // gate g^1
        float t2 = __shfl_xor(v, 2, 64);  // gate g^2
        float t3 = __shfl_xor(v, 3, 64);  // gate g^3
        float fv = (g == 0) ? v : (g == 1) ? t1 : (g == 2) ? t2 : t3;
        float iv = (g == 1) ? v : (g == 0) ? t1 : (g == 3) ? t2 : t3;
        float gv = (g == 2) ? v : (g == 3) ? t1 : (g == 0) ? t2 : t3;
        float ov = (g == 3) ? v : (g == 2) ? t1 : (g == 1) ? t2 : t3;
        int m = m0 + r;
        float cp = c_prev[(size_t)m * HH + h];
        float ft = 1.f / (1.f + __expf(-fv));
        float it = 1.f / (1.f + __expf(-iv));
        float gt = tanhf(gv);
        float ot = 1.f / (1.f + __expf(-ov));
        float cn = ft * cp + it * gt;
        float hn = ot * tanhf(cn);
        if (g == 0)      out[(size_t)m * HH + h] = hn;
        else if (g == 1) out[(size_t)BB * HH + (size_t)m * HH + h] = cn;
      }
    }
}

// ---- fallback (only if ws too small): naive fp32 ----
__global__ void lstm_naive(const float* __restrict__ x, const float* __restrict__ hp,
                           const float* __restrict__ cp,
                           const float* __restrict__ Wf, const float* __restrict__ bf_,
                           const float* __restrict__ Wi, const float* __restrict__ bi_,
                           const float* __restrict__ Wg, const float* __restrict__ bg_,
                           const float* __restrict__ Wo, const float* __restrict__ bo_,
                           float* __restrict__ out) {
  size_t idx = (size_t)blockIdx.x * 256 + threadIdx.x;
  int b = (int)(idx >> 10), h = (int)(idx & 1023);
  float sf = bf_[h], si = bi_[h], sg = bg_[h], so = bo_[h];
  const float* xr = x + (size_t)b * 1024;
  const float* hr = hp + (size_t)b * 1024;
  const float* wf = Wf + (size_t)h * KK;
  const float* wi = Wi + (size_t)h * KK;
  const float* wg = Wg + (size_t)h * KK;
  const float* wo = Wo + (size_t)h * KK;
  for (int k = 0; k < 1024; ++k) {
    float a = xr[k];
    sf += a * wf[k]; si += a * wi[k]; sg += a * wg[k]; so += a * wo[k];
  }
  for (int k = 0; k < 1024; ++k) {
    float a = hr[k];
    sf += a * wf[1024 + k]; si += a * wi[1024 + k];
    sg += a * wg[1024 + k]; so += a * wo[1024 + k];
  }
  float ft = 1.f / (1.f + expf(-sf));
  float it = 1.f / (1.f + expf(-si));
  float gt = tanhf(sg);
  float ot = 1.f / (1.f + expf(-so));
  float cn = ft * cp[idx] + it * gt;
  out[idx] = ot * tanhf(cn);
  out[(size_t)BB * HH + idx] = cn;
}

extern "C" void kernel_launch(void* const* d_in, const int* in_sizes, int n_in,
                              void* d_out, int out_size, void* d_ws, size_t ws_size,
                              hipStream_t stream) {
  const float* x  = (const float*)d_in[0];
  const float* hp = (const float*)d_in[1];
  const float* cp = (const float*)d_in[2];
  const float* Wf = (const float*)d_in[3];  const float* bf_ = (const float*)d_in[4];
  const float* Wi = (const float*)d_in[5];  const float* bi_ = (const float*)d_in[6];
  const float* Wg = (const float*)d_in[7];  const float* bg_ = (const float*)d_in[8];
  const float* Wo = (const float*)d_in[9];  const float* bo_ = (const float*)d_in[10];
  float* out = (float*)d_out;

  const size_t offAhi = 0;
  const size_t offAlo = (size_t)BB * KK * 2;              // 64 MiB
  const size_t offWhi = offAlo + (size_t)BB * KK * 2;     // 128 MiB
  const size_t offWlo = offWhi + (size_t)NN * KK * 2;     // 144 MiB
  const size_t offBp  = offWlo + (size_t)NN * KK * 2;     // 160 MiB
  const size_t needed = offBp + (size_t)NN * 4;

  if (ws_size < needed) {
    lstm_naive<<<(BB * HH) / 256, 256, 0, stream>>>(x, hp, cp, Wf, bf_, Wi, bi_, Wg, bg_, Wo, bo_, out);
    return;
  }

  ushort* Ahi = (ushort*)((char*)d_ws + offAhi);
  ushort* Alo = (ushort*)((char*)d_ws + offAlo);
  ushort* WhiP = (ushort*)((char*)d_ws + offWhi);
  ushort* WloP = (ushort*)((char*)d_ws + offWlo);
  float*  bpack = (float*)((char*)d_ws + offBp);

  prep_A<<<(BB * KK / 8) / 256, 256, 0, stream>>>(x, hp, Ahi, Alo);
  prep_W<<<(NN * KK / 8) / 256, 256, 0, stream>>>(Wf, Wi, Wg, Wo, bf_, bi_, bg_, bo_, WhiP, WloP, bpack);
  lstm_gemm<<<dim3(NN / 128, BB / 128), 256, 0, stream>>>(Ahi, Alo, WhiP, WloP, bpack, cp, out);
}